// Round 3
// baseline (36280.051 us; speedup 1.0000x reference)
//
#include <hip/hip_runtime.h>
#include <math.h>

// Problem: bidirectional GRU encoder. V=32000, D=512, H=512, L=512, B=64.
// xp layout: [L][B][1536], h layout: [B][512]

#define NBLK 128  // persistent scan blocks; 128 blocks @ 1 block/CU -> co-resident

// ---- bf16 storage helpers (fallback path when ws is small) ----------------
static __device__ __forceinline__ unsigned short f2bf(float x) {
    union { float f; unsigned u; } c; c.f = x;
    unsigned r = c.u + 0x7fffu + ((c.u >> 16) & 1u);   // RNE
    return (unsigned short)(r >> 16);
}
static __device__ __forceinline__ float bf2f(unsigned short s) {
    union { unsigned u; float f; } c; c.u = ((unsigned)s) << 16;
    return c.f;
}
static __device__ __forceinline__ void store_out(float* p, const float4& v) {
    *(float4*)p = v;
}
static __device__ __forceinline__ void store_out(unsigned short* p, const float4& v) {
    uint2 u;
    u.x = (unsigned)f2bf(v.x) | ((unsigned)f2bf(v.y) << 16);
    u.y = (unsigned)f2bf(v.z) | ((unsigned)f2bf(v.w) << 16);
    *(uint2*)p = u;
}
static __device__ __forceinline__ float load_x(const float* p)          { return *p; }
static __device__ __forceinline__ float load_x(const unsigned short* p) { return bf2f(*p); }

static __device__ __forceinline__ void grid_barrier(int* bar, int target) {
    __syncthreads();
    if (threadIdx.x == 0) {
        __threadfence();                    // agent-scope release (L2 writeback on gfx950)
        atomicAdd(bar, 1);                  // device-scope by default
        while (__hip_atomic_load(bar, __ATOMIC_ACQUIRE, __HIP_MEMORY_SCOPE_AGENT) < target) {
            __builtin_amdgcn_s_sleep(1);
        }
        // acquire on the atomic load -> L1/L2 invalidate before data reads
    }
    __syncthreads();
}

// ---------------------------------------------------------------------------
// GEMM: out[m][n] = sum_k A[row(m)][k] * W[k][n] + bias[n]
// A rows are 512 floats; W is (512,1536); optional row gather via idx.
// Tiles: BM=128, BN=64, BK=16; 256 threads; 8x4 micro-tile per thread.
// ---------------------------------------------------------------------------
template <typename XT>
__global__ __launch_bounds__(256, 2)
void gemm_xp(const float* __restrict__ A, const int* __restrict__ idx,
             const float* __restrict__ W, const float* __restrict__ bias,
             XT* __restrict__ out)
{
    __shared__ float As[16][132];   // [k][m], +4 pad -> 2-way alias max (free)
    __shared__ float Bs[16][64];    // [k][n]
    __shared__ int rowidx[128];

    const int tid = threadIdx.x;
    const int m0 = blockIdx.y * 128;
    const int n0 = blockIdx.x * 64;
    if (tid < 128) rowidx[tid] = idx ? idx[m0 + tid] : (m0 + tid);
    __syncthreads();

    const int tx = tid & 15, ty = tid >> 4;
    float acc[8][4];
    #pragma unroll
    for (int i = 0; i < 8; ++i)
        #pragma unroll
        for (int jq = 0; jq < 4; ++jq) acc[i][jq] = 0.f;

    for (int k0 = 0; k0 < 512; k0 += 16) {
        #pragma unroll
        for (int i = 0; i < 8; ++i) {
            int e = i * 256 + tid;
            int k = e & 15, m = e >> 4;
            As[k][m] = A[(size_t)rowidx[m] * 512 + k0 + k];
        }
        #pragma unroll
        for (int i = 0; i < 4; ++i) {
            int e = i * 256 + tid;
            int n = e & 63, k = e >> 6;
            Bs[k][n] = W[(size_t)(k0 + k) * 1536 + n0 + n];
        }
        __syncthreads();
        #pragma unroll
        for (int k = 0; k < 16; ++k) {
            float a[8], b[4];
            #pragma unroll
            for (int i = 0; i < 8; ++i) a[i] = As[k][ty * 8 + i];
            #pragma unroll
            for (int jq = 0; jq < 4; ++jq) b[jq] = Bs[k][tx * 4 + jq];
            #pragma unroll
            for (int i = 0; i < 8; ++i)
                #pragma unroll
                for (int jq = 0; jq < 4; ++jq)
                    acc[i][jq] = fmaf(a[i], b[jq], acc[i][jq]);
        }
        __syncthreads();
    }

    float bz[4];
    #pragma unroll
    for (int jq = 0; jq < 4; ++jq) bz[jq] = bias[n0 + tx * 4 + jq];
    #pragma unroll
    for (int i = 0; i < 8; ++i) {
        float4 v = make_float4(acc[i][0] + bz[0], acc[i][1] + bz[1],
                               acc[i][2] + bz[2], acc[i][3] + bz[3]);
        store_out(&out[(size_t)(m0 + ty * 8 + i) * 1536 + n0 + tx * 4], v);
    }
}

// ---------------------------------------------------------------------------
// Persistent GRU scan. Grid = NBLK blocks x 256 threads.
// Block b owns output columns j0..j0+3 (j0 = b*4). Thread (s, jj):
// s = tid>>2 in [0,64), jj = tid&3. Per step: phase1 = z,r gates + write r*h;
// grid barrier; phase2 = hh + h update; grid barrier.
// ---------------------------------------------------------------------------
template <typename XT>
__global__ __launch_bounds__(256, 1)
void gru_scan(const XT* __restrict__ xp,     // [L][64][1536]
              const float* __restrict__ U,   // [512][1536]
              const float* __restrict__ mask,// [L][64]
              float* __restrict__ hbuf,      // [64][512], pre-zeroed (h0)
              float* __restrict__ rh,        // [64][512]
              float* __restrict__ outp,      // [L][64][512]
              int* __restrict__ bar,         // pre-zeroed
              int reverse)
{
    __shared__ float Uz[4][512], Ur[4][512], Uh[4][512];  // 24 KB
    const int tid = threadIdx.x;
    const int j0 = blockIdx.x * 4;

    for (int e = tid; e < 2048; e += 256) {
        int jj = e >> 9, k = e & 511;
        Uz[jj][k] = U[(size_t)k * 1536 + j0 + jj];
        Ur[jj][k] = U[(size_t)k * 1536 + 512 + j0 + jj];
        Uh[jj][k] = U[(size_t)k * 1536 + 1024 + j0 + jj];
    }
    __syncthreads();

    const int s = tid >> 2, jj = tid & 3;
    const int j = j0 + jj;
    const float* uz = Uz[jj];
    const float* ur = Ur[jj];
    const float* uh = Uh[jj];
    const float4* h4 = (const float4*)hbuf;
    const float4* r4 = (const float4*)rh;

    for (int step = 0; step < 512; ++step) {
        const int l = reverse ? (511 - step) : step;
        const XT* xpl = xp + (size_t)(l * 64 + s) * 1536;
        const float xz = load_x(xpl + j);
        const float xr = load_x(xpl + 512 + j);
        const float xh = load_x(xpl + 1024 + j);
        const float m = mask[l * 64 + s];
        const float hsj = hbuf[s * 512 + j];

        // ---- phase 1: z, r gates (dot over full previous h)
        float az[4] = {0.f, 0.f, 0.f, 0.f};
        float ar[4] = {0.f, 0.f, 0.f, 0.f};
        for (int q = 0; q < 32; ++q) {
            #pragma unroll
            for (int p = 0; p < 4; ++p) {
                float4 hv = h4[s * 128 + q * 4 + p];
                int k = q * 16 + p * 4;
                az[p] = fmaf(hv.x, uz[k + 0], az[p]);
                az[p] = fmaf(hv.y, uz[k + 1], az[p]);
                az[p] = fmaf(hv.z, uz[k + 2], az[p]);
                az[p] = fmaf(hv.w, uz[k + 3], az[p]);
                ar[p] = fmaf(hv.x, ur[k + 0], ar[p]);
                ar[p] = fmaf(hv.y, ur[k + 1], ar[p]);
                ar[p] = fmaf(hv.z, ur[k + 2], ar[p]);
                ar[p] = fmaf(hv.w, ur[k + 3], ar[p]);
            }
        }
        const float accz = xz + ((az[0] + az[1]) + (az[2] + az[3]));
        const float accr = xr + ((ar[0] + ar[1]) + (ar[2] + ar[3]));
        const float z = 1.f / (1.f + expf(-accz));
        const float r = 1.f / (1.f + expf(-accr));
        rh[s * 512 + j] = r * hsj;

        grid_barrier(bar, NBLK * (2 * step + 1));

        // ---- phase 2: candidate hh, h update
        float ah[4] = {0.f, 0.f, 0.f, 0.f};
        for (int q = 0; q < 32; ++q) {
            #pragma unroll
            for (int p = 0; p < 4; ++p) {
                float4 rv = r4[s * 128 + q * 4 + p];
                int k = q * 16 + p * 4;
                ah[p] = fmaf(rv.x, uh[k + 0], ah[p]);
                ah[p] = fmaf(rv.y, uh[k + 1], ah[p]);
                ah[p] = fmaf(rv.z, uh[k + 2], ah[p]);
                ah[p] = fmaf(rv.w, uh[k + 3], ah[p]);
            }
        }
        const float acch = xh + ((ah[0] + ah[1]) + (ah[2] + ah[3]));
        const float hh = tanhf(acch);
        float hn = (1.f - z) * hsj + z * hh;
        hn = m * hn + (1.f - m) * hsj;

        outp[(size_t)(l * 64 + s) * 512 + j] = hn;
        hbuf[s * 512 + j] = hn;

        grid_barrier(bar, NBLK * (2 * step + 2));
    }
}

// ---------------------------------------------------------------------------
// Workspace layout (fp32 path, ~193 MB):
//   [0,256)            barrier counter fwd
//   [256,512)          barrier counter bwd
//   [4096, +128K)      hbuf fwd (zeroed -> h0)
//   [+128K, +128K)     hbuf bwd
//   [+128K, +128K)     rh scratch
//   [1MB, +192MB)      xp (xpf, reused for xpb)   [bf16 path: +96MB]
// `right` (fwd scan output, 64 MB f32) lives in d_out: it is fully consumed
// by GEMM#2 before the backward scan overwrites d_out with `left`.
// ---------------------------------------------------------------------------
extern "C" void kernel_launch(void* const* d_in, const int* in_sizes, int n_in,
                              void* d_out, int out_size, void* d_ws, size_t ws_size,
                              hipStream_t stream)
{
    const int*   xs   = (const int*)  d_in[0];
    const float* mask = (const float*)d_in[1];
    const float* emb  = (const float*)d_in[2];
    const float* Wf   = (const float*)d_in[3];
    const float* Uf   = (const float*)d_in[4];
    const float* bf   = (const float*)d_in[5];
    const float* Wb   = (const float*)d_in[6];
    const float* Ub   = (const float*)d_in[7];
    const float* bb   = (const float*)d_in[8];
    float* out = (float*)d_out;

    char* w = (char*)d_ws;
    int*   bar0  = (int*)(w + 0);
    int*   bar1  = (int*)(w + 256);
    float* hbufF = (float*)(w + 4096);
    float* hbufB = (float*)(w + 4096 + 131072);
    float* rhb   = (float*)(w + 4096 + 262144);
    char*  xpb_  = w + (1u << 20);
    float* right = out;   // d_out doubles as scratch for the forward scan output

    hipMemsetAsync(d_ws, 0, 4096 + 3 * 131072, stream);

    const size_t need_f32 = (1u << 20) + (size_t)512 * 64 * 1536 * 4;
    dim3 gg(24, 256), bg(256);

    if (ws_size >= need_f32) {
        float* xp = (float*)xpb_;
        gemm_xp<float><<<gg, bg, 0, stream>>>(emb, xs, Wf, bf, xp);
        gru_scan<float><<<NBLK, 256, 0, stream>>>(xp, Uf, mask, hbufF, rhb, right, bar0, 0);
        gemm_xp<float><<<gg, bg, 0, stream>>>(right, nullptr, Wb, bb, xp);
        gru_scan<float><<<NBLK, 256, 0, stream>>>(xp, Ub, mask, hbufB, rhb, out, bar1, 1);
    } else {
        unsigned short* xp = (unsigned short*)xpb_;
        gemm_xp<unsigned short><<<gg, bg, 0, stream>>>(emb, xs, Wf, bf, xp);
        gru_scan<unsigned short><<<NBLK, 256, 0, stream>>>(xp, Uf, mask, hbufF, rhb, right, bar0, 0);
        gemm_xp<unsigned short><<<gg, bg, 0, stream>>>(right, nullptr, Wb, bb, xp);
        gru_scan<unsigned short><<<NBLK, 256, 0, stream>>>(xp, Ub, mask, hbufB, rhb, out, bar1, 1);
    }
}

// Round 4
// 24219.104 us; speedup vs baseline: 1.4980x; 1.4980x over previous
//
#include <hip/hip_runtime.h>
#include <math.h>

// Problem: bidirectional GRU encoder. V=32000, D=512, H=512, L=512, B=64.
// xp layout: [L][B][1536], h layout: [B][512]

#define NBLK 128  // persistent scan blocks; co-resident on 256 CUs

// ---- bf16 storage helpers (xp fallback when ws is small; this path ran r3) --
static __device__ __forceinline__ unsigned short f2bf(float x) {
    union { float f; unsigned u; } c; c.f = x;
    unsigned r = c.u + 0x7fffu + ((c.u >> 16) & 1u);   // RNE
    return (unsigned short)(r >> 16);
}
static __device__ __forceinline__ float bf2f(unsigned short s) {
    union { unsigned u; float f; } c; c.u = ((unsigned)s) << 16;
    return c.f;
}
static __device__ __forceinline__ void store_out(float* p, const float4& v) {
    *(float4*)p = v;
}
static __device__ __forceinline__ void store_out(unsigned short* p, const float4& v) {
    uint2 u;
    u.x = (unsigned)f2bf(v.x) | ((unsigned)f2bf(v.y) << 16);
    u.y = (unsigned)f2bf(v.z) | ((unsigned)f2bf(v.w) << 16);
    *(uint2*)p = u;
}
static __device__ __forceinline__ float load_x(const float* p)          { return *p; }
static __device__ __forceinline__ float load_x(const unsigned short* p) { return bf2f(*p); }

// LLC write-through store (4B): visible device-wide once vmcnt drains.
static __device__ __forceinline__ void st_llc(float* p, float v) {
    __hip_atomic_store(p, v, __ATOMIC_RELAXED, __HIP_MEMORY_SCOPE_AGENT);
}

// ---------------------------------------------------------------------------
// GEMM: out[m][n] = sum_k A[row(m)][k] * W[k][n] + bias[n]  (unchanged, ~150us)
// ---------------------------------------------------------------------------
template <typename XT>
__global__ __launch_bounds__(256, 2)
void gemm_xp(const float* __restrict__ A, const int* __restrict__ idx,
             const float* __restrict__ W, const float* __restrict__ bias,
             XT* __restrict__ out)
{
    __shared__ float As[16][132];
    __shared__ float Bs[16][64];
    __shared__ int rowidx[128];

    const int tid = threadIdx.x;
    const int m0 = blockIdx.y * 128;
    const int n0 = blockIdx.x * 64;
    if (tid < 128) rowidx[tid] = idx ? idx[m0 + tid] : (m0 + tid);
    __syncthreads();

    const int tx = tid & 15, ty = tid >> 4;
    float acc[8][4];
    #pragma unroll
    for (int i = 0; i < 8; ++i)
        #pragma unroll
        for (int jq = 0; jq < 4; ++jq) acc[i][jq] = 0.f;

    for (int k0 = 0; k0 < 512; k0 += 16) {
        #pragma unroll
        for (int i = 0; i < 8; ++i) {
            int e = i * 256 + tid;
            int k = e & 15, m = e >> 4;
            As[k][m] = A[(size_t)rowidx[m] * 512 + k0 + k];
        }
        #pragma unroll
        for (int i = 0; i < 4; ++i) {
            int e = i * 256 + tid;
            int n = e & 63, k = e >> 6;
            Bs[k][n] = W[(size_t)(k0 + k) * 1536 + n0 + n];
        }
        __syncthreads();
        #pragma unroll
        for (int k = 0; k < 16; ++k) {
            float a[8], b[4];
            #pragma unroll
            for (int i = 0; i < 8; ++i) a[i] = As[k][ty * 8 + i];
            #pragma unroll
            for (int jq = 0; jq < 4; ++jq) b[jq] = Bs[k][tx * 4 + jq];
            #pragma unroll
            for (int i = 0; i < 8; ++i)
                #pragma unroll
                for (int jq = 0; jq < 4; ++jq)
                    acc[i][jq] = fmaf(a[i], b[jq], acc[i][jq]);
        }
        __syncthreads();
    }

    float bz[4];
    #pragma unroll
    for (int jq = 0; jq < 4; ++jq) bz[jq] = bias[n0 + tx * 4 + jq];
    #pragma unroll
    for (int i = 0; i < 8; ++i) {
        float4 v = make_float4(acc[i][0] + bz[0], acc[i][1] + bz[1],
                               acc[i][2] + bz[2], acc[i][3] + bz[3]);
        store_out(&out[(size_t)(m0 + ty * 8 + i) * 1536 + n0 + tx * 4], v);
    }
}

// ---------------------------------------------------------------------------
// Persistent GRU scan, fence-light barrier edition.
// Cross-block protocol per phase:
//   producer: st_llc(value)  -> s_waitcnt vmcnt(0) per thread -> __syncthreads
//             -> thread0: RELAXED fetch_add (arrival)
//   consumer: thread0 polls RELAXED (no cache maintenance), then ONE
//             ACQUIRE load (buffer_inv; L1+L2 of this CU/XCD invalidated)
//             -> __syncthreads -> plain cached float4 reads see fresh data.
// LDS U slices padded [4][520]: jj banks {0,8,16,24} -> conflict-free b128.
// ---------------------------------------------------------------------------
template <typename XT>
__global__ __launch_bounds__(256, 1)
void gru_scan(const XT* __restrict__ xp,     // [L][64][1536]
              const float* __restrict__ U,   // [512][1536]
              const float* __restrict__ mask,// [L][64]
              float* __restrict__ hbuf,      // [64][512], pre-zeroed (h0)
              float* __restrict__ rh,        // [64][512]
              float* __restrict__ outp,      // [L][64][512]
              int* __restrict__ bar,         // pre-zeroed
              int reverse)
{
    __shared__ float Uz[4][520], Ur[4][520], Uh[4][520];  // ~25 KB, padded
    const int tid = threadIdx.x;
    const int j0 = blockIdx.x * 4;

    for (int e = tid; e < 2048; e += 256) {
        int jj = e >> 9, k = e & 511;
        Uz[jj][k] = U[(size_t)k * 1536 + j0 + jj];
        Ur[jj][k] = U[(size_t)k * 1536 + 512 + j0 + jj];
        Uh[jj][k] = U[(size_t)k * 1536 + 1024 + j0 + jj];
    }
    __syncthreads();

    const int s = tid >> 2, jj = tid & 3;
    const int j = j0 + jj;
    const float* uz = Uz[jj];
    const float* ur = Ur[jj];
    const float* uh = Uh[jj];
    const float4* h4 = (const float4*)hbuf;
    const float4* r4 = (const float4*)rh;

    for (int step = 0; step < 512; ++step) {
        const int l = reverse ? (511 - step) : step;
        const XT* xpl = xp + (size_t)(l * 64 + s) * 1536;
        const float xz = load_x(xpl + j);
        const float xr = load_x(xpl + 512 + j);
        const float xh = load_x(xpl + 1024 + j);
        const float m = mask[l * 64 + s];
        const float hsj = hbuf[s * 512 + j];

        // ---- phase 1: z, r gates (dot over full previous h)
        float az[4] = {0.f, 0.f, 0.f, 0.f};
        float ar[4] = {0.f, 0.f, 0.f, 0.f};
        for (int q = 0; q < 32; ++q) {
            #pragma unroll
            for (int p = 0; p < 4; ++p) {
                float4 hv = h4[s * 128 + q * 4 + p];
                int k = q * 16 + p * 4;
                az[p] = fmaf(hv.x, uz[k + 0], az[p]);
                az[p] = fmaf(hv.y, uz[k + 1], az[p]);
                az[p] = fmaf(hv.z, uz[k + 2], az[p]);
                az[p] = fmaf(hv.w, uz[k + 3], az[p]);
                ar[p] = fmaf(hv.x, ur[k + 0], ar[p]);
                ar[p] = fmaf(hv.y, ur[k + 1], ar[p]);
                ar[p] = fmaf(hv.z, ur[k + 2], ar[p]);
                ar[p] = fmaf(hv.w, ur[k + 3], ar[p]);
            }
        }
        const float accz = xz + ((az[0] + az[1]) + (az[2] + az[3]));
        const float accr = xr + ((ar[0] + ar[1]) + (ar[2] + ar[3]));
        const float z = 1.f / (1.f + expf(-accz));
        const float r = 1.f / (1.f + expf(-accr));
        st_llc(&rh[s * 512 + j], r * hsj);
        asm volatile("s_waitcnt vmcnt(0)" ::: "memory");  // my store is at LLC
        __syncthreads();                                   // whole block's stores are
        if (tid == 0) {
            __hip_atomic_fetch_add(bar, 1, __ATOMIC_RELAXED, __HIP_MEMORY_SCOPE_AGENT);
            const int tgt = NBLK * (2 * step + 1);
            while (__hip_atomic_load(bar, __ATOMIC_RELAXED, __HIP_MEMORY_SCOPE_AGENT) < tgt)
                __builtin_amdgcn_s_sleep(1);
            (void)__hip_atomic_load(bar, __ATOMIC_ACQUIRE, __HIP_MEMORY_SCOPE_AGENT); // one inv
        }
        __syncthreads();

        // ---- phase 2: candidate hh, h update
        float ah[4] = {0.f, 0.f, 0.f, 0.f};
        for (int q = 0; q < 32; ++q) {
            #pragma unroll
            for (int p = 0; p < 4; ++p) {
                float4 rv = r4[s * 128 + q * 4 + p];
                int k = q * 16 + p * 4;
                ah[p] = fmaf(rv.x, uh[k + 0], ah[p]);
                ah[p] = fmaf(rv.y, uh[k + 1], ah[p]);
                ah[p] = fmaf(rv.z, uh[k + 2], ah[p]);
                ah[p] = fmaf(rv.w, uh[k + 3], ah[p]);
            }
        }
        const float acch = xh + ((ah[0] + ah[1]) + (ah[2] + ah[3]));
        const float hh = tanhf(acch);
        float hn = (1.f - z) * hsj + z * hh;
        hn = m * hn + (1.f - m) * hsj;

        outp[(size_t)(l * 64 + s) * 512 + j] = hn;   // plain store; kernel-end release
        st_llc(&hbuf[s * 512 + j], hn);
        asm volatile("s_waitcnt vmcnt(0)" ::: "memory");
        __syncthreads();
        if (tid == 0) {
            __hip_atomic_fetch_add(bar, 1, __ATOMIC_RELAXED, __HIP_MEMORY_SCOPE_AGENT);
            const int tgt = NBLK * (2 * step + 2);
            while (__hip_atomic_load(bar, __ATOMIC_RELAXED, __HIP_MEMORY_SCOPE_AGENT) < tgt)
                __builtin_amdgcn_s_sleep(1);
            (void)__hip_atomic_load(bar, __ATOMIC_ACQUIRE, __HIP_MEMORY_SCOPE_AGENT);
        }
        __syncthreads();
    }
}

// ---------------------------------------------------------------------------
// Workspace layout:
//   [0,256) bar fwd | [256,512) bar bwd | [4096,+128K) hbufF | +128K hbufB
//   | +128K rh | [1MB, ...) xp (fp32 192MB or bf16 96MB)
// `right` lives in d_out (consumed by GEMM#2 before bwd scan overwrites).
// ---------------------------------------------------------------------------
extern "C" void kernel_launch(void* const* d_in, const int* in_sizes, int n_in,
                              void* d_out, int out_size, void* d_ws, size_t ws_size,
                              hipStream_t stream)
{
    const int*   xs   = (const int*)  d_in[0];
    const float* mask = (const float*)d_in[1];
    const float* emb  = (const float*)d_in[2];
    const float* Wf   = (const float*)d_in[3];
    const float* Uf   = (const float*)d_in[4];
    const float* bf   = (const float*)d_in[5];
    const float* Wb   = (const float*)d_in[6];
    const float* Ub   = (const float*)d_in[7];
    const float* bb   = (const float*)d_in[8];
    float* out = (float*)d_out;

    char* w = (char*)d_ws;
    int*   bar0  = (int*)(w + 0);
    int*   bar1  = (int*)(w + 256);
    float* hbufF = (float*)(w + 4096);
    float* hbufB = (float*)(w + 4096 + 131072);
    float* rhb   = (float*)(w + 4096 + 262144);
    char*  xpb_  = w + (1u << 20);
    float* right = out;

    hipMemsetAsync(d_ws, 0, 4096 + 3 * 131072, stream);

    const size_t need_f32 = (1u << 20) + (size_t)512 * 64 * 1536 * 4;
    dim3 gg(24, 256), bg(256);

    if (ws_size >= need_f32) {
        float* xp = (float*)xpb_;
        gemm_xp<float><<<gg, bg, 0, stream>>>(emb, xs, Wf, bf, xp);
        gru_scan<float><<<NBLK, 256, 0, stream>>>(xp, Uf, mask, hbufF, rhb, right, bar0, 0);
        gemm_xp<float><<<gg, bg, 0, stream>>>(right, nullptr, Wb, bb, xp);
        gru_scan<float><<<NBLK, 256, 0, stream>>>(xp, Ub, mask, hbufB, rhb, out, bar1, 1);
    } else {
        unsigned short* xp = (unsigned short*)xpb_;
        gemm_xp<unsigned short><<<gg, bg, 0, stream>>>(emb, xs, Wf, bf, xp);
        gru_scan<unsigned short><<<NBLK, 256, 0, stream>>>(xp, Uf, mask, hbufF, rhb, right, bar0, 0);
        gemm_xp<unsigned short><<<gg, bg, 0, stream>>>(right, nullptr, Wb, bb, xp);
        gru_scan<unsigned short><<<NBLK, 256, 0, stream>>>(xp, Ub, mask, hbufB, rhb, out, bar1, 1);
    }
}